// Round 8
// baseline (188.001 us; speedup 1.0000x reference)
//
#include <hip/hip_runtime.h>

// Problem: B=8, S=2048, H=1024, D=64. fp32 in, fp32 out.
// out = softmax_causal(q k^T) / sqrt(H) @ v   (softmax FIRST, then /32)

typedef float     f32x4 __attribute__((ext_vector_type(4)));
typedef _Float16  f16x8 __attribute__((ext_vector_type(8)));
typedef _Float16  f16x4 __attribute__((ext_vector_type(4)));

#define L2E 1.44269504088896340736f

// ---------------------------------------------------------------------------
// Kernel 1: pack W{q,k,v} into MFMA B-fragment order (f16) via LDS transpose.
// Frag (kstep*12+nt)*64+lane holds 8 f16: W[n=nt*16+(lane&15)][k=kstep*32+(lane>>4)*8+j]
__global__ __launch_bounds__(256) void wt_prep(const float* __restrict__ Wq,
                                               const float* __restrict__ Wk,
                                               const float* __restrict__ Wv,
                                               _Float16* __restrict__ WtF) {
  const int w  = blockIdx.x >> 4;              // which W
  const int kt = blockIdx.x & 15;              // k-tile of 64
  const float* src = (w == 0) ? Wq : (w == 1 ? Wk : Wv);
  __shared__ _Float16 ls[64][72];
  const int t = threadIdx.x;
  {
    int rr = t >> 4;
    int c4 = (t & 15) * 4;
    #pragma unroll
    for (int ri = 0; ri < 4; ++ri) {
      int k = rr + ri * 16;
      f32x4 f = *(const f32x4*)&src[(size_t)(kt * 64 + k) * 64 + c4];
      #pragma unroll
      for (int j = 0; j < 4; ++j) ls[k][c4 + j] = (_Float16)f[j];
    }
  }
  __syncthreads();
  const int lane = t & 63, l16 = lane & 15, quad = lane >> 4;
  #pragma unroll
  for (int h = 0; h < 2; ++h) {
    int fid     = h * 4 + (t >> 6);
    int kstep_l = fid >> 2;
    int ntl     = fid & 3;
    int nt      = w * 4 + ntl;
    int kstep   = kt * 2 + kstep_l;
    f16x8 o;
    #pragma unroll
    for (int j = 0; j < 8; ++j) o[j] = ls[kstep_l * 32 + quad * 8 + j][ntl * 16 + l16];
    *(f16x8*)&WtF[((size_t)(kstep * 12 + nt) * 64 + lane) * 8] = o;
  }
}

// ---------------------------------------------------------------------------
// Kernel 2: QKV projection, LDS-free, EXPLICIT software pipeline.
// Round-7 evidence: VGPR_Count=32 -> compiler serialized every K-step behind
// vmcnt(0) (55us, VALUBusy 4.5%). Here next iteration's 5 loads are issued in
// program order BEFORE current data is consumed (named prefetch regs), forcing
// >=2 iterations in flight and vmcnt(N>0) waits. Grid 1024 (M-tile=16),
// 4 waves x 3 n-tiles.
__global__ __launch_bounds__(256) void qkv_gemm(const float* __restrict__ x,
                                                const _Float16* __restrict__ WtF,
                                                const float* __restrict__ bq,
                                                const float* __restrict__ bk,
                                                const float* __restrict__ bv,
                                                _Float16* __restrict__ qo,
                                                _Float16* __restrict__ ko,
                                                _Float16* __restrict__ vt) {
  const int tid  = threadIdx.x;
  const int wave = tid >> 6, lane = tid & 63;
  const int l16  = lane & 15, quad = lane >> 4;
  const int m0   = blockIdx.x * 16;

  f32x4 acc0 = (f32x4){0.f,0.f,0.f,0.f};
  f32x4 acc1 = (f32x4){0.f,0.f,0.f,0.f};
  f32x4 acc2 = (f32x4){0.f,0.f,0.f,0.f};

  const float* ap = x + (size_t)(m0 + l16) * 1024 + quad * 8;
  const _Float16* wbase = WtF + ((size_t)(wave * 3) * 64 + lane) * 8;

  // prologue: load k=0
  f32x4 ca0 = *(const f32x4*)(ap);
  f32x4 ca1 = *(const f32x4*)(ap + 4);
  f16x8 cb0 = *(const f16x8*)(wbase);
  f16x8 cb1 = *(const f16x8*)(wbase + 512);
  f16x8 cb2 = *(const f16x8*)(wbase + 1024);

  #pragma unroll
  for (int kstep = 0; kstep < 32; ++kstep) {
    f32x4 na0, na1; f16x8 nb0, nb1, nb2;
    if (kstep < 31) {                          // prefetch k+1 BEFORE consuming k
      const float* apn = ap + (kstep + 1) * 32;
      na0 = *(const f32x4*)(apn);
      na1 = *(const f32x4*)(apn + 4);
      const _Float16* wkn = wbase + (size_t)(kstep + 1) * (12 * 64 * 8);
      nb0 = *(const f16x8*)(wkn);
      nb1 = *(const f16x8*)(wkn + 512);
      nb2 = *(const f16x8*)(wkn + 1024);
    }
    f16x8 a;
    #pragma unroll
    for (int j = 0; j < 4; ++j) { a[j] = (_Float16)ca0[j]; a[4 + j] = (_Float16)ca1[j]; }
    acc0 = __builtin_amdgcn_mfma_f32_16x16x32_f16(a, cb0, acc0, 0, 0, 0);
    acc1 = __builtin_amdgcn_mfma_f32_16x16x32_f16(a, cb1, acc1, 0, 0, 0);
    acc2 = __builtin_amdgcn_mfma_f32_16x16x32_f16(a, cb2, acc2, 0, 0, 0);
    ca0 = na0; ca1 = na1; cb0 = nb0; cb1 = nb1; cb2 = nb2;  // dead on last iter
  }

  // epilogue: C/D col=lane&15, row=quad*4+r. Bias add, f16 write.
  f32x4 accs[3] = {acc0, acc1, acc2};
  #pragma unroll
  for (int i = 0; i < 3; ++i) {
    int nt  = wave * 3 + i;
    int col = nt * 16 + l16;
    float bias = (nt < 4) ? bq[col] : (nt < 8) ? bk[col - 64] : bv[col - 128];
    #pragma unroll
    for (int r = 0; r < 4; ++r) {
      int m = m0 + quad * 4 + r;               // global row = b*2048+s
      _Float16 hv = (_Float16)(accs[i][r] + bias);
      if (nt < 4)      qo[(size_t)m * 64 + col] = hv;
      else if (nt < 8) ko[(size_t)m * 64 + (col - 64)] = hv;
      else {                                   // v stored transposed: vt[b][d][s]
        int b = m >> 11, s = m & 2047;
        vt[((size_t)b * 64 + (col - 128)) * 2048 + s] = hv;
      }
    }
  }
}

// ---------------------------------------------------------------------------
// Kernel 3: causal attention (round-4 structure + XCD swizzle + V PREFETCH).
// V-fragment addresses are known at wave start -> all 8 v-loads issued before
// the QK MFMAs, hiding their latency behind score compute + softmax.
// 1-D grid 4608: b = blk&7 pins batch b's 768KB q/k/vt set in one XCD's L2.
// q-tile qt has (qt>>4)+1 splits of 256 kv; 4 waves take 64 kv each ->
// single max/sum; scores kv-major (C col=q, row=kv). In-block LDS merge;
// g=0 writes out directly.
__global__ __launch_bounds__(256) void attn(const _Float16* __restrict__ q,
                                            const _Float16* __restrict__ k,
                                            const _Float16* __restrict__ vt,
                                            _Float16* __restrict__ po,
                                            float* __restrict__ pm,
                                            float* __restrict__ pl,
                                            float* __restrict__ out) {
  const int blk = blockIdx.x;
  const int b   = blk & 7;                     // XCD affinity
  const int bid = 575 - (blk >> 3);            // heavy-first
  int g = 0;                                   // group: qt in [16g,16g+16), g+1 splits
  #pragma unroll
  for (int gg = 0; gg < 7; ++gg) if (bid >= 8 * (gg + 1) * (gg + 2)) g = gg + 1;
  const int r   = bid - 8 * g * (g + 1);
  const int qi  = r / (g + 1);                 // 0..15 (uniform, once)
  const int qt  = 16 * g + qi;
  const int s   = r - qi * (g + 1);            // split 0..g
  const int q0  = qt * 16, kvend = q0 + 16;

  const int tid  = threadIdx.x;
  const int wave = tid >> 6, lane = tid & 63;
  const int l16  = lane & 15, quad = lane >> 4;
  const int kv0  = s * 256 + wave * 64;

  __shared__ float ow[4][64][17];              // per-wave O^T[d][q]; [wave] aliases P
  __shared__ float mw[4][16], lw[4][16];
  _Float16* Plw = (_Float16*)&ow[wave][0][0];  // per-wave P buffer [16 q][72 kv]

  float m = -1e30f, l = 0.f;
  f32x4 o[4];
  #pragma unroll
  for (int i = 0; i < 4; ++i) o[i] = (f32x4){0.f, 0.f, 0.f, 0.f};

  if (kv0 < kvend) {                           // wave-uniform
    const _Float16* qb = q  + (size_t)b * 2048 * 64;
    const _Float16* kb = k  + (size_t)b * 2048 * 64;
    const _Float16* vb = vt + (size_t)b * 64 * 2048;
    // Q as B-operand: B[k=d=quad*8+j][n=q=l16]
    f16x8 qf0 = *(const f16x8*)&qb[(size_t)(q0 + l16) * 64 + quad * 8];
    f16x8 qf1 = *(const f16x8*)&qb[(size_t)(q0 + l16) * 64 + 32 + quad * 8];
    // V PREFETCH: Vt as A-frags, A[m=d=l16][k=kv=quad*8+j]; in-bounds always
    f16x8 vf0[4], vf1[4];
    #pragma unroll
    for (int dt = 0; dt < 4; ++dt) {
      vf0[dt] = *(const f16x8*)&vb[(size_t)(dt * 16 + l16) * 2048 + kv0 + quad * 8];
      vf1[dt] = *(const f16x8*)&vb[(size_t)(dt * 16 + l16) * 2048 + kv0 + 32 + quad * 8];
    }

    f32x4 sc[4];
    #pragma unroll
    for (int t = 0; t < 4; ++t) {
      int kvc = kv0 + t * 16;
      if (kvc < kvend) {                       // K as A: A[m=kv=l16][k=d]
        f16x8 kf0 = *(const f16x8*)&kb[(size_t)(kvc + l16) * 64 + quad * 8];
        f16x8 kf1 = *(const f16x8*)&kb[(size_t)(kvc + l16) * 64 + 32 + quad * 8];
        f32x4 c = (f32x4){0.f, 0.f, 0.f, 0.f};
        c = __builtin_amdgcn_mfma_f32_16x16x32_f16(kf0, qf0, c, 0, 0, 0);
        c = __builtin_amdgcn_mfma_f32_16x16x32_f16(kf1, qf1, c, 0, 0, 0);
        sc[t] = c;
      } else sc[t] = (f32x4){-1e30f, -1e30f, -1e30f, -1e30f};
    }
    // causal mask: row = kv = kvc+quad*4+rr, col = q = q0+l16
    if (kv0 + 63 > q0) {
      #pragma unroll
      for (int t = 0; t < 4; ++t) {
        #pragma unroll
        for (int rr = 0; rr < 4; ++rr) {
          int skv = kv0 + t * 16 + quad * 4 + rr;
          if (skv > q0 + l16) sc[t][rr] = -1e30f;
        }
      }
    }
    // softmax over kv for fixed q=l16: 15 in-lane + 2 shuffles
    float mx = sc[0][0];
    #pragma unroll
    for (int t = 0; t < 4; ++t)
      #pragma unroll
      for (int rr = 0; rr < 4; ++rr) mx = fmaxf(mx, sc[t][rr]);
    mx = fmaxf(mx, __shfl_xor(mx, 16, 64));
    mx = fmaxf(mx, __shfl_xor(mx, 32, 64));
    m = mx;
    float sum = 0.f;
    #pragma unroll
    for (int t = 0; t < 4; ++t)
      #pragma unroll
      for (int rr = 0; rr < 4; ++rr) {
        float e = exp2f((sc[t][rr] - m) * L2E);  // masked -> 0
        sc[t][rr] = e;
        sum += e;
      }
    sum += __shfl_xor(sum, 16, 64);
    sum += __shfl_xor(sum, 32, 64);
    l = sum;
    // P -> LDS [q][kv] with vectorized f16x4 writes (rr = consecutive kv)
    #pragma unroll
    for (int t = 0; t < 4; ++t) {
      f16x4 ph;
      #pragma unroll
      for (int rr = 0; rr < 4; ++rr) ph[rr] = (_Float16)sc[t][rr];
      *(f16x4*)&Plw[l16 * 72 + t * 16 + quad * 4] = ph;
    }
    asm volatile("s_waitcnt lgkmcnt(0)" ::: "memory");   // per-wave DS drain
    f16x8 p0 = *(const f16x8*)&Plw[l16 * 72 + quad * 8];
    f16x8 p1 = *(const f16x8*)&Plw[l16 * 72 + 32 + quad * 8];
    // O^T[d][q] += Vt[d][kv] * P[kv][q]  (v already resident)
    #pragma unroll
    for (int dt = 0; dt < 4; ++dt) {
      o[dt] = __builtin_amdgcn_mfma_f32_16x16x32_f16(vf0[dt], p0, o[dt], 0, 0, 0);
      o[dt] = __builtin_amdgcn_mfma_f32_16x16x32_f16(vf1[dt], p1, o[dt], 0, 0, 0);
    }
  }

  __syncthreads();                             // all Plw reads done before ow overwrite
  #pragma unroll
  for (int dt = 0; dt < 4; ++dt)
    #pragma unroll
    for (int rr = 0; rr < 4; ++rr)
      ow[wave][dt * 16 + quad * 4 + rr][l16] = o[dt][rr];
  if (quad == 0) { mw[wave][l16] = m; lw[wave][l16] = l; }
  __syncthreads();

  // merge 4 waves; thread t -> q = t>>4, d = (t&15)*4 .. +3
  {
    int qrow = tid >> 4, d4 = (tid & 15) * 4;
    float m0v = mw[0][qrow], m1v = mw[1][qrow], m2v = mw[2][qrow], m3v = mw[3][qrow];
    float M = fmaxf(fmaxf(m0v, m1v), fmaxf(m2v, m3v));
    float w0 = exp2f((m0v - M) * L2E), w1 = exp2f((m1v - M) * L2E);
    float w2 = exp2f((m2v - M) * L2E), w3 = exp2f((m3v - M) * L2E);
    float L = w0 * lw[0][qrow] + w1 * lw[1][qrow] + w2 * lw[2][qrow] + w3 * lw[3][qrow];
    float O0 = w0 * ow[0][d4 + 0][qrow] + w1 * ow[1][d4 + 0][qrow]
             + w2 * ow[2][d4 + 0][qrow] + w3 * ow[3][d4 + 0][qrow];
    float O1 = w0 * ow[0][d4 + 1][qrow] + w1 * ow[1][d4 + 1][qrow]
             + w2 * ow[2][d4 + 1][qrow] + w3 * ow[3][d4 + 1][qrow];
    float O2 = w0 * ow[0][d4 + 2][qrow] + w1 * ow[1][d4 + 2][qrow]
             + w2 * ow[2][d4 + 2][qrow] + w3 * ow[3][d4 + 2][qrow];
    float O3 = w0 * ow[0][d4 + 3][qrow] + w1 * ow[1][d4 + 3][qrow]
             + w2 * ow[2][d4 + 3][qrow] + w3 * ow[3][d4 + 3][qrow];
    if (g == 0) {                              // single split: final output
      float inv = 1.0f / (L * 32.0f);          // sqrt(H)=32 applied AFTER softmax
      f32x4 res = (f32x4){O0 * inv, O1 * inv, O2 * inv, O3 * inv};
      *(f32x4*)&out[((size_t)b * 2048 + q0 + qrow) * 64 + d4] = res;
    } else {
      size_t pid = (size_t)b * 576 + bid;
      f16x4 oh;
      oh[0] = (_Float16)O0; oh[1] = (_Float16)O1;
      oh[2] = (_Float16)O2; oh[3] = (_Float16)O3;
      *(f16x4*)&po[pid * 1024 + (size_t)qrow * 64 + d4] = oh;
      if ((tid & 15) == 0) { pm[pid * 16 + qrow] = M; pl[pid * 16 + qrow] = L; }
    }
  }
}

// ---------------------------------------------------------------------------
// Kernel 4: merge the (qt>>4)+1 splits of q-tiles 16..127, normalize, write.
__global__ __launch_bounds__(256) void attn_merge(const _Float16* __restrict__ po,
                                                  const float* __restrict__ pm,
                                                  const float* __restrict__ pl,
                                                  float* __restrict__ out) {
  const int qt = 16 + blockIdx.x, b = blockIdx.y;
  const int g = qt >> 4, S = g + 1;
  const size_t base = (size_t)b * 576 + (size_t)(g + 1) * (8 * g + (qt & 15));
  const int t = threadIdx.x, qrow = t >> 4, d4 = (t & 15) * 4;

  float M = -1e30f;
  for (int s = 0; s < S; ++s) M = fmaxf(M, pm[(base + s) * 16 + qrow]);
  float L = 0.f;
  float O0 = 0.f, O1 = 0.f, O2 = 0.f, O3 = 0.f;
  for (int s = 0; s < S; ++s) {
    float w = exp2f((pm[(base + s) * 16 + qrow] - M) * L2E);
    L += w * pl[(base + s) * 16 + qrow];
    f16x4 ov = *(const f16x4*)&po[(base + s) * 1024 + (size_t)qrow * 64 + d4];
    O0 += w * (float)ov[0]; O1 += w * (float)ov[1];
    O2 += w * (float)ov[2]; O3 += w * (float)ov[3];
  }
  float inv = 1.0f / (L * 32.0f);              // sqrt(H)=32 applied AFTER softmax
  f32x4 res = (f32x4){O0 * inv, O1 * inv, O2 * inv, O3 * inv};
  *(f32x4*)&out[((size_t)b * 2048 + qt * 16 + qrow) * 64 + d4] = res;
}

// ---------------------------------------------------------------------------
extern "C" void kernel_launch(void* const* d_in, const int* in_sizes, int n_in,
                              void* d_out, int out_size, void* d_ws, size_t ws_size,
                              hipStream_t stream) {
  const float* x  = (const float*)d_in[0];
  const float* Wq = (const float*)d_in[1];
  const float* bq = (const float*)d_in[2];
  const float* Wk = (const float*)d_in[3];
  const float* bk = (const float*)d_in[4];
  const float* Wv = (const float*)d_in[5];
  const float* bv = (const float*)d_in[6];
  float* out = (float*)d_out;

  // ws: WtF 384KB | q 2MB | k 2MB | vt 2MB | po 9.4MB f16 | pm/pl 576KB f32
  _Float16* WtF = (_Float16*)d_ws;
  _Float16* qo  = WtF + 192 * 1024;
  _Float16* ko  = qo + 16384 * 64;
  _Float16* vt  = ko + 16384 * 64;
  _Float16* po  = vt + 8 * 64 * 2048;
  float*    pm  = (float*)(po + (size_t)4608 * 1024);
  float*    pl  = pm + 4608 * 16;

  hipLaunchKernelGGL(wt_prep,    dim3(48),      dim3(256), 0, stream, Wq, Wk, Wv, WtF);
  hipLaunchKernelGGL(qkv_gemm,   dim3(1024),    dim3(256), 0, stream, x, WtF, bq, bk, bv, qo, ko, vt);
  hipLaunchKernelGGL(attn,       dim3(4608),    dim3(256), 0, stream, qo, ko, vt, po, pm, pl, out);
  hipLaunchKernelGGL(attn_merge, dim3(112, 8),  dim3(256), 0, stream, po, pm, pl, out);
}

// Round 9
// 164.505 us; speedup vs baseline: 1.1428x; 1.1428x over previous
//
#include <hip/hip_runtime.h>

// Problem: B=8, S=2048, H=1024, D=64. fp32 in, fp32 out.
// out = softmax_causal(q k^T) / sqrt(H) @ v   (softmax FIRST, then /32)

typedef float     f32x4 __attribute__((ext_vector_type(4)));
typedef _Float16  f16x8 __attribute__((ext_vector_type(8)));
typedef _Float16  f16x4 __attribute__((ext_vector_type(4)));

#define L2E 1.44269504088896340736f

// async global->LDS copy, 16B per lane (dst must be wave-uniform base + lane*16)
__device__ __forceinline__ void cp16(void* lds, const void* g) {
  __builtin_amdgcn_global_load_lds(
      (const __attribute__((address_space(1))) unsigned int*)g,
      (__attribute__((address_space(3))) unsigned int*)lds, 16, 0, 0);
}

// ---------------------------------------------------------------------------
// Kernel 1: pack W{q,k,v} into MFMA B-fragment order (f16) via LDS transpose.
// Frag (kstep*12+nt)*64+lane holds 8 f16: W[n=nt*16+(lane&15)][k=kstep*32+(lane>>4)*8+j]
__global__ __launch_bounds__(256) void wt_prep(const float* __restrict__ Wq,
                                               const float* __restrict__ Wk,
                                               const float* __restrict__ Wv,
                                               _Float16* __restrict__ WtF) {
  const int w  = blockIdx.x >> 4;              // which W
  const int kt = blockIdx.x & 15;              // k-tile of 64
  const float* src = (w == 0) ? Wq : (w == 1 ? Wk : Wv);
  __shared__ _Float16 ls[64][72];
  const int t = threadIdx.x;
  {
    int rr = t >> 4;
    int c4 = (t & 15) * 4;
    #pragma unroll
    for (int ri = 0; ri < 4; ++ri) {
      int k = rr + ri * 16;
      f32x4 f = *(const f32x4*)&src[(size_t)(kt * 64 + k) * 64 + c4];
      #pragma unroll
      for (int j = 0; j < 4; ++j) ls[k][c4 + j] = (_Float16)f[j];
    }
  }
  __syncthreads();
  const int lane = t & 63, l16 = lane & 15, quad = lane >> 4;
  #pragma unroll
  for (int h = 0; h < 2; ++h) {
    int fid     = h * 4 + (t >> 6);
    int kstep_l = fid >> 2;
    int ntl     = fid & 3;
    int nt      = w * 4 + ntl;
    int kstep   = kt * 2 + kstep_l;
    f16x8 o;
    #pragma unroll
    for (int j = 0; j < 8; ++j) o[j] = ls[kstep_l * 32 + quad * 8 + j][ntl * 16 + l16];
    *(f16x8*)&WtF[((size_t)(kstep * 12 + nt) * 64 + lane) * 8] = o;
  }
}

// ---------------------------------------------------------------------------
// Kernel 2: QKV projection, m97-style DMA pipeline (rounds 3/7/8 all pinned at
// ~55us with compiler-scheduled global streaming; global_load_lds + dbuf LDS +
// barrier pacing is the measured-working escape). Grid 256 (M-tile=64),
// 512 thr (8 waves = 2 mgrp x 4 ngrp x 3 n-tiles), BK=64, 16 chunks.
// B chunk (24KB, frag-order contiguous in WtF) via global_load_lds (linear).
// A chunk (64x64 f16 = 8KB) staged manually: f32x8 load + cvt + XOR-swizzled
// ds_write (granule ^ row&7 -> <=2-way on write and frag-read).
// Pipeline: [barrier][issue A loads c+1][issue B DMA c+1][compute c][cvt+write c+1].
__global__ __launch_bounds__(512) void qkv_gemm(const float* __restrict__ x,
                                                const _Float16* __restrict__ WtF,
                                                const float* __restrict__ bq,
                                                const float* __restrict__ bk,
                                                const float* __restrict__ bv,
                                                _Float16* __restrict__ qo,
                                                _Float16* __restrict__ ko,
                                                _Float16* __restrict__ vt) {
  __shared__ _Float16 Ab[2][64 * 64];          // 2 x 8KB
  __shared__ _Float16 Bb[2][12288];            // 2 x 24KB
  const int tid  = threadIdx.x;
  const int wave = tid >> 6, lane = tid & 63;
  const int l16  = lane & 15, quad = lane >> 4;
  const int mgrp = wave >> 2;                  // 0..1: rows mgrp*32 .. +31
  const int ngrp = wave & 3;                   // 0..3: n-tiles ngrp*3 .. +2
  const int m0   = blockIdx.x * 64;

  // A staging map: thread t -> row = t>>3 (0..63), granule g = t&7 (16B = 8 f16)
  const int arow = tid >> 3, ag = tid & 7;
  const float* asrc = x + (size_t)(m0 + arow) * 1024 + ag * 8;
  _Float16* adst_base[2] = {
    &Ab[0][arow * 64 + ((ag ^ (arow & 7)) * 8)],
    &Ab[1][arow * 64 + ((ag ^ (arow & 7)) * 8)] };

  // B staging: 3 x 16B per thread, linear
  const _Float16* bsrc = WtF + (size_t)tid * 8;
  f32x4 acc[2][3];
  #pragma unroll
  for (int rg = 0; rg < 2; ++rg)
    #pragma unroll
    for (int i = 0; i < 3; ++i) acc[rg][i] = (f32x4){0.f, 0.f, 0.f, 0.f};

  // prologue: stage chunk 0
  {
    f32x4 a0 = *(const f32x4*)(asrc);
    f32x4 a1 = *(const f32x4*)(asrc + 4);
    #pragma unroll
    for (int i = 0; i < 3; ++i)
      cp16(&Bb[0][i * 4096 + tid * 8], bsrc + (size_t)i * 4096);
    f16x8 h;
    #pragma unroll
    for (int j = 0; j < 4; ++j) { h[j] = (_Float16)a0[j]; h[4 + j] = (_Float16)a1[j]; }
    *(f16x8*)adst_base[0] = h;
  }

  for (int c = 0; c < 16; ++c) {
    const int cur = c & 1, nxt = cur ^ 1;
    __syncthreads();                           // drains vmcnt+lgkmcnt: buf[cur] ready
    f32x4 a0, a1;
    if (c < 15) {                              // issue next A loads + B DMA now
      a0 = *(const f32x4*)(asrc + (c + 1) * 64);
      a1 = *(const f32x4*)(asrc + (c + 1) * 64 + 4);
      const _Float16* bs = bsrc + (size_t)(c + 1) * 12288;
      #pragma unroll
      for (int i = 0; i < 3; ++i)
        cp16(&Bb[nxt][i * 4096 + tid * 8], bs + (size_t)i * 4096);
    }
    // compute chunk c: 2 ksteps x (2 A frags + 3 B frags)
    #pragma unroll
    for (int ks = 0; ks < 2; ++ks) {
      f16x8 af[2], bf[3];
      #pragma unroll
      for (int rg = 0; rg < 2; ++rg) {
        int row = mgrp * 32 + rg * 16 + l16;
        af[rg] = *(const f16x8*)&Ab[cur][row * 64 + (((ks * 4 + quad) ^ (row & 7)) * 8)];
      }
      #pragma unroll
      for (int i = 0; i < 3; ++i)
        bf[i] = *(const f16x8*)&Bb[cur][(ks * 12 + ngrp * 3 + i) * 512 + lane * 8];
      #pragma unroll
      for (int rg = 0; rg < 2; ++rg)
        #pragma unroll
        for (int i = 0; i < 3; ++i)
          acc[rg][i] = __builtin_amdgcn_mfma_f32_16x16x32_f16(af[rg], bf[i], acc[rg][i], 0, 0, 0);
    }
    if (c < 15) {                              // convert + swizzled write AFTER compute
      f16x8 h;
      #pragma unroll
      for (int j = 0; j < 4; ++j) { h[j] = (_Float16)a0[j]; h[4 + j] = (_Float16)a1[j]; }
      *(f16x8*)adst_base[nxt] = h;
    }
  }

  // epilogue: C/D col=lane&15, row=quad*4+r. Bias add, f16 write.
  #pragma unroll
  for (int rg = 0; rg < 2; ++rg) {
    #pragma unroll
    for (int i = 0; i < 3; ++i) {
      int nt  = ngrp * 3 + i;
      int col = nt * 16 + l16;
      float bias = (nt < 4) ? bq[col] : (nt < 8) ? bk[col - 64] : bv[col - 128];
      #pragma unroll
      for (int r = 0; r < 4; ++r) {
        int m = m0 + mgrp * 32 + rg * 16 + quad * 4 + r;   // global row = b*2048+s
        _Float16 hv = (_Float16)(acc[rg][i][r] + bias);
        if (nt < 4)      qo[(size_t)m * 64 + col] = hv;
        else if (nt < 8) ko[(size_t)m * 64 + (col - 64)] = hv;
        else {                                 // v stored transposed: vt[b][d][s]
          int b = m >> 11, s = m & 2047;
          vt[((size_t)b * 64 + (col - 128)) * 2048 + s] = hv;
        }
      }
    }
  }
}

// ---------------------------------------------------------------------------
// Kernel 3: causal attention (round-4 structure + XCD swizzle + V prefetch).
// 1-D grid 4608: b = blk&7 pins batch b's 768KB q/k/vt set in one XCD's L2.
// q-tile qt has (qt>>4)+1 splits of 256 kv; 4 waves take 64 kv each ->
// single max/sum; scores kv-major (C col=q, row=kv). In-block LDS merge;
// g=0 writes out directly.
__global__ __launch_bounds__(256) void attn(const _Float16* __restrict__ q,
                                            const _Float16* __restrict__ k,
                                            const _Float16* __restrict__ vt,
                                            _Float16* __restrict__ po,
                                            float* __restrict__ pm,
                                            float* __restrict__ pl,
                                            float* __restrict__ out) {
  const int blk = blockIdx.x;
  const int b   = blk & 7;                     // XCD affinity
  const int bid = 575 - (blk >> 3);            // heavy-first
  int g = 0;                                   // group: qt in [16g,16g+16), g+1 splits
  #pragma unroll
  for (int gg = 0; gg < 7; ++gg) if (bid >= 8 * (gg + 1) * (gg + 2)) g = gg + 1;
  const int r   = bid - 8 * g * (g + 1);
  const int qi  = r / (g + 1);                 // 0..15 (uniform, once)
  const int qt  = 16 * g + qi;
  const int s   = r - qi * (g + 1);            // split 0..g
  const int q0  = qt * 16, kvend = q0 + 16;

  const int tid  = threadIdx.x;
  const int wave = tid >> 6, lane = tid & 63;
  const int l16  = lane & 15, quad = lane >> 4;
  const int kv0  = s * 256 + wave * 64;

  __shared__ float ow[4][64][17];              // per-wave O^T[d][q]; [wave] aliases P
  __shared__ float mw[4][16], lw[4][16];
  _Float16* Plw = (_Float16*)&ow[wave][0][0];  // per-wave P buffer [16 q][72 kv]

  float m = -1e30f, l = 0.f;
  f32x4 o[4];
  #pragma unroll
  for (int i = 0; i < 4; ++i) o[i] = (f32x4){0.f, 0.f, 0.f, 0.f};

  if (kv0 < kvend) {                           // wave-uniform
    const _Float16* qb = q  + (size_t)b * 2048 * 64;
    const _Float16* kb = k  + (size_t)b * 2048 * 64;
    const _Float16* vb = vt + (size_t)b * 64 * 2048;
    // Q as B-operand: B[k=d=quad*8+j][n=q=l16]
    f16x8 qf0 = *(const f16x8*)&qb[(size_t)(q0 + l16) * 64 + quad * 8];
    f16x8 qf1 = *(const f16x8*)&qb[(size_t)(q0 + l16) * 64 + 32 + quad * 8];
    // V prefetch: Vt as A-frags, A[m=d=l16][k=kv=quad*8+j]
    f16x8 vf0[4], vf1[4];
    #pragma unroll
    for (int dt = 0; dt < 4; ++dt) {
      vf0[dt] = *(const f16x8*)&vb[(size_t)(dt * 16 + l16) * 2048 + kv0 + quad * 8];
      vf1[dt] = *(const f16x8*)&vb[(size_t)(dt * 16 + l16) * 2048 + kv0 + 32 + quad * 8];
    }

    f32x4 sc[4];
    #pragma unroll
    for (int t = 0; t < 4; ++t) {
      int kvc = kv0 + t * 16;
      if (kvc < kvend) {                       // K as A: A[m=kv=l16][k=d]
        f16x8 kf0 = *(const f16x8*)&kb[(size_t)(kvc + l16) * 64 + quad * 8];
        f16x8 kf1 = *(const f16x8*)&kb[(size_t)(kvc + l16) * 64 + 32 + quad * 8];
        f32x4 c = (f32x4){0.f, 0.f, 0.f, 0.f};
        c = __builtin_amdgcn_mfma_f32_16x16x32_f16(kf0, qf0, c, 0, 0, 0);
        c = __builtin_amdgcn_mfma_f32_16x16x32_f16(kf1, qf1, c, 0, 0, 0);
        sc[t] = c;
      } else sc[t] = (f32x4){-1e30f, -1e30f, -1e30f, -1e30f};
    }
    // causal mask: row = kv = kvc+quad*4+rr, col = q = q0+l16
    if (kv0 + 63 > q0) {
      #pragma unroll
      for (int t = 0; t < 4; ++t) {
        #pragma unroll
        for (int rr = 0; rr < 4; ++rr) {
          int skv = kv0 + t * 16 + quad * 4 + rr;
          if (skv > q0 + l16) sc[t][rr] = -1e30f;
        }
      }
    }
    // softmax over kv for fixed q=l16: 15 in-lane + 2 shuffles
    float mx = sc[0][0];
    #pragma unroll
    for (int t = 0; t < 4; ++t)
      #pragma unroll
      for (int rr = 0; rr < 4; ++rr) mx = fmaxf(mx, sc[t][rr]);
    mx = fmaxf(mx, __shfl_xor(mx, 16, 64));
    mx = fmaxf(mx, __shfl_xor(mx, 32, 64));
    m = mx;
    float sum = 0.f;
    #pragma unroll
    for (int t = 0; t < 4; ++t)
      #pragma unroll
      for (int rr = 0; rr < 4; ++rr) {
        float e = exp2f((sc[t][rr] - m) * L2E);  // masked -> 0
        sc[t][rr] = e;
        sum += e;
      }
    sum += __shfl_xor(sum, 16, 64);
    sum += __shfl_xor(sum, 32, 64);
    l = sum;
    // P -> LDS [q][kv] with vectorized f16x4 writes (rr = consecutive kv)
    #pragma unroll
    for (int t = 0; t < 4; ++t) {
      f16x4 ph;
      #pragma unroll
      for (int rr = 0; rr < 4; ++rr) ph[rr] = (_Float16)sc[t][rr];
      *(f16x4*)&Plw[l16 * 72 + t * 16 + quad * 4] = ph;
    }
    asm volatile("s_waitcnt lgkmcnt(0)" ::: "memory");   // per-wave DS drain
    f16x8 p0 = *(const f16x8*)&Plw[l16 * 72 + quad * 8];
    f16x8 p1 = *(const f16x8*)&Plw[l16 * 72 + 32 + quad * 8];
    // O^T[d][q] += Vt[d][kv] * P[kv][q]  (v already resident)
    #pragma unroll
    for (int dt = 0; dt < 4; ++dt) {
      o[dt] = __builtin_amdgcn_mfma_f32_16x16x32_f16(vf0[dt], p0, o[dt], 0, 0, 0);
      o[dt] = __builtin_amdgcn_mfma_f32_16x16x32_f16(vf1[dt], p1, o[dt], 0, 0, 0);
    }
  }

  __syncthreads();                             // all Plw reads done before ow overwrite
  #pragma unroll
  for (int dt = 0; dt < 4; ++dt)
    #pragma unroll
    for (int rr = 0; rr < 4; ++rr)
      ow[wave][dt * 16 + quad * 4 + rr][l16] = o[dt][rr];
  if (quad == 0) { mw[wave][l16] = m; lw[wave][l16] = l; }
  __syncthreads();

  // merge 4 waves; thread t -> q = t>>4, d = (t&15)*4 .. +3
  {
    int qrow = tid >> 4, d4 = (tid & 15) * 4;
    float m0v = mw[0][qrow], m1v = mw[1][qrow], m2v = mw[2][qrow], m3v = mw[3][qrow];
    float M = fmaxf(fmaxf(m0v, m1v), fmaxf(m2v, m3v));
    float w0 = exp2f((m0v - M) * L2E), w1 = exp2f((m1v - M) * L2E);
    float w2 = exp2f((m2v - M) * L2E), w3 = exp2f((m3v - M) * L2E);
    float L = w0 * lw[0][qrow] + w1 * lw[1][qrow] + w2 * lw[2][qrow] + w3 * lw[3][qrow];
    float O0 = w0 * ow[0][d4 + 0][qrow] + w1 * ow[1][d4 + 0][qrow]
             + w2 * ow[2][d4 + 0][qrow] + w3 * ow[3][d4 + 0][qrow];
    float O1 = w0 * ow[0][d4 + 1][qrow] + w1 * ow[1][d4 + 1][qrow]
             + w2 * ow[2][d4 + 1][qrow] + w3 * ow[3][d4 + 1][qrow];
    float O2 = w0 * ow[0][d4 + 2][qrow] + w1 * ow[1][d4 + 2][qrow]
             + w2 * ow[2][d4 + 2][qrow] + w3 * ow[3][d4 + 2][qrow];
    float O3 = w0 * ow[0][d4 + 3][qrow] + w1 * ow[1][d4 + 3][qrow]
             + w2 * ow[2][d4 + 3][qrow] + w3 * ow[3][d4 + 3][qrow];
    if (g == 0) {                              // single split: final output
      float inv = 1.0f / (L * 32.0f);          // sqrt(H)=32 applied AFTER softmax
      f32x4 res = (f32x4){O0 * inv, O1 * inv, O2 * inv, O3 * inv};
      *(f32x4*)&out[((size_t)b * 2048 + q0 + qrow) * 64 + d4] = res;
    } else {
      size_t pid = (size_t)b * 576 + bid;
      f16x4 oh;
      oh[0] = (_Float16)O0; oh[1] = (_Float16)O1;
      oh[2] = (_Float16)O2; oh[3] = (_Float16)O3;
      *(f16x4*)&po[pid * 1024 + (size_t)qrow * 64 + d4] = oh;
      if ((tid & 15) == 0) { pm[pid * 16 + qrow] = M; pl[pid * 16 + qrow] = L; }
    }
  }
}

// ---------------------------------------------------------------------------
// Kernel 4: merge the (qt>>4)+1 splits of q-tiles 16..127, normalize, write.
__global__ __launch_bounds__(256) void attn_merge(const _Float16* __restrict__ po,
                                                  const float* __restrict__ pm,
                                                  const float* __restrict__ pl,
                                                  float* __restrict__ out) {
  const int qt = 16 + blockIdx.x, b = blockIdx.y;
  const int g = qt >> 4, S = g + 1;
  const size_t base = (size_t)b * 576 + (size_t)(g + 1) * (8 * g + (qt & 15));
  const int t = threadIdx.x, qrow = t >> 4, d4 = (t & 15) * 4;

  float M = -1e30f;
  for (int s = 0; s < S; ++s) M = fmaxf(M, pm[(base + s) * 16 + qrow]);
  float L = 0.f;
  float O0 = 0.f, O1 = 0.f, O2 = 0.f, O3 = 0.f;
  for (int s = 0; s < S; ++s) {
    float w = exp2f((pm[(base + s) * 16 + qrow] - M) * L2E);
    L += w * pl[(base + s) * 16 + qrow];
    f16x4 ov = *(const f16x4*)&po[(base + s) * 1024 + (size_t)qrow * 64 + d4];
    O0 += w * (float)ov[0]; O1 += w * (float)ov[1];
    O2 += w * (float)ov[2]; O3 += w * (float)ov[3];
  }
  float inv = 1.0f / (L * 32.0f);              // sqrt(H)=32 applied AFTER softmax
  f32x4 res = (f32x4){O0 * inv, O1 * inv, O2 * inv, O3 * inv};
  *(f32x4*)&out[((size_t)b * 2048 + qt * 16 + qrow) * 64 + d4] = res;
}

// ---------------------------------------------------------------------------
extern "C" void kernel_launch(void* const* d_in, const int* in_sizes, int n_in,
                              void* d_out, int out_size, void* d_ws, size_t ws_size,
                              hipStream_t stream) {
  const float* x  = (const float*)d_in[0];
  const float* Wq = (const float*)d_in[1];
  const float* bq = (const float*)d_in[2];
  const float* Wk = (const float*)d_in[3];
  const float* bk = (const float*)d_in[4];
  const float* Wv = (const float*)d_in[5];
  const float* bv = (const float*)d_in[6];
  float* out = (float*)d_out;

  // ws: WtF 384KB | q 2MB | k 2MB | vt 2MB | po 9.4MB f16 | pm/pl 576KB f32
  _Float16* WtF = (_Float16*)d_ws;
  _Float16* qo  = WtF + 192 * 1024;
  _Float16* ko  = qo + 16384 * 64;
  _Float16* vt  = ko + 16384 * 64;
  _Float16* po  = vt + 8 * 64 * 2048;
  float*    pm  = (float*)(po + (size_t)4608 * 1024);
  float*    pl  = pm + 4608 * 16;

  hipLaunchKernelGGL(wt_prep,    dim3(48),      dim3(256), 0, stream, Wq, Wk, Wv, WtF);
  hipLaunchKernelGGL(qkv_gemm,   dim3(256),     dim3(512), 0, stream, x, WtF, bq, bk, bv, qo, ko, vt);
  hipLaunchKernelGGL(attn,       dim3(4608),    dim3(256), 0, stream, qo, ko, vt, po, pm, pl, out);
  hipLaunchKernelGGL(attn_merge, dim3(112, 8),  dim3(256), 0, stream, po, pm, pl, out);
}